// Round 8
// baseline (1264.597 us; speedup 1.0000x reference)
//
#include <hip/hip_runtime.h>
#include <math.h>

typedef _Float16 half8 __attribute__((ext_vector_type(8)));
typedef _Float16 half4v __attribute__((ext_vector_type(4)));
typedef float float4v __attribute__((ext_vector_type(4)));

constexpr int Lc   = 2048;  // L_IN
constexpr int DECc = 64;    // DEC_LEN
constexpr int Hc   = 128;   // H
constexpr int EMBc = 16;    // EMB
constexpr int INc  = 18;    // IN_SIZE
constexpr int NBc  = 4;     // batches per block
constexpr int NTc  = 512;   // 8 waves
constexpr int KT   = 4;     // k-tiles of 32 -- h only (x handled via table)
constexpr int CARD = 200;
constexpr int ZS   = 160;   // z stride per batch (halves); 320B -> 2-way (free) on b128 reads
constexpr int TBL  = CARD * 512;   // one table: [cat][cell][gt] f16

// R8: the x-part of the gates (emb(cat)*Wih[:,0:16]) is PRECOMPUTED as a
// 200x512 f16 table in global workspace (cat has only 200 values) by a tiny
// prep kernel. The recurrent GEMM is then h-only: 4 K-tiles, 16 MFMAs/wave/step
// (pipe 776 -> 621 cy/SIMD). Per step the lane adds, after sel4:
//   gate += xg[gt] (table, b64 global load prefetched ONE FULL STEP ahead)
//         + cont*w16[gt] + X*w17[gt]   (rank-2 columns, registers)
// No x-writer role, z = pure h. Decoder: mu feedback as rank-1 w17 term
// through mu_lds (validated R2), same table mechanism with cat_out.

__device__ __forceinline__ float rcp_(float x) { return __builtin_amdgcn_rcpf(x); }
__device__ __forceinline__ float sigm(float x) { return rcp_(1.0f + __expf(-x)); }
__device__ __forceinline__ float tanh_(float x) { return 2.0f * rcp_(1.0f + __expf(-2.0f * x)) - 1.0f; }
__device__ __forceinline__ float softplus_(float x) { return __logf(1.0f + __expf(x)); }

// dynamic 4-element select (3 cndmask)
__device__ __forceinline__ float sel4(float4v v, int q) {
    const float a = (q & 1) ? v[1] : v[0];
    const float b = (q & 1) ? v[3] : v[2];
    return (q & 2) ? b : a;
}

// ---------- prep: emb->gate tables for encoder and decoder Wih ----------
__global__ __launch_bounds__(512, 1) void prep_kernel(
    const float* __restrict__ emb_table,
    const float* __restrict__ Wih_e, const float* __restrict__ Wih_d,
    _Float16* __restrict__ ws)
{
    const int c = blockIdx.x;    // 0..199
    const int g = threadIdx.x;   // 0..511 (gate row)
    __shared__ float e[EMBc];
    if (threadIdx.x < EMBc) e[threadIdx.x] = emb_table[c * EMBc + threadIdx.x];
    __syncthreads();
    float s0 = 0.f, s1 = 0.f;
    #pragma unroll
    for (int k = 0; k < EMBc; ++k) {
        s0 += e[k] * Wih_e[g * INc + k];
        s1 += e[k] * Wih_d[g * INc + k];
    }
    const int cell = g & 127, gt = g >> 7;   // [cat][cell][gt]
    ws[c * 512 + cell * 4 + gt]       = (_Float16)s0;
    ws[TBL + c * 512 + cell * 4 + gt] = (_Float16)s1;
}

__global__ __launch_bounds__(NTc, 1) void rnnar_kernel(
    const int*   __restrict__ cat_in,  const float* __restrict__ cont_in,
    const float* __restrict__ X_in,    const int*   __restrict__ cat_out,
    const float* __restrict__ cont_out,const float* __restrict__ emb_table,
    const float* __restrict__ cont_w,
    const float* __restrict__ Wih_e, const float* __restrict__ Whh_e, const float* __restrict__ b_e,
    const float* __restrict__ Wih_d, const float* __restrict__ Whh_d, const float* __restrict__ b_d,
    const float* __restrict__ Wm, const float* __restrict__ bm,
    const float* __restrict__ Ws, const float* __restrict__ bs,
    const float* __restrict__ Wv, const float* __restrict__ bv,
    const _Float16* __restrict__ xtab,   // ws: [0..TBL) encoder, [TBL..2TBL) decoder
    float* __restrict__ out)
{
    __shared__ _Float16      z_lds[2][NBc * ZS];   // 2.5 KB double-buffered h, [b][k]
    __shared__ _Float16      xs04[Lc * NBc];       // 16 KB [t][b] cont_in * w00
    __shared__ _Float16      xs14[Lc * NBc];       // 16 KB [t][b] X_in
    __shared__ unsigned char catb4[Lc * NBc];      // 8 KB  [t][b]
    __shared__ _Float16      xo4[DECc * NBc];      // 512 B [t][b] cont_out * w00
    __shared__ unsigned char catob4[DECc * NBc];   // 256 B [t][b]
    __shared__ float         h32_lds[NBc * 132];   // 2.1 KB
    __shared__ float         wh_lds[6 * Hc];       // 3 KB
    __shared__ float         hb_lds[8];
    __shared__ float         mu_lds[4];

    const int tid  = threadIdx.x;
    const int lane = tid & 63;
    const int wv   = tid >> 6;        // wave 0..7
    const int q    = lane >> 4;       // quad 0..3 = this lane's batch
    const int col  = lane & 15;       // cell-local 0..15
    const int cell = 16 * wv + col;   // this lane's cell
    const int bx   = col & 3;         // A-frag batch
    const int b0   = blockIdx.x * NBc;
    const float w00 = cont_w[0];

    // ---------------- staging ----------------
    {
        int* z32 = (int*)&z_lds[0][0];
        for (int i = tid; i < NBc * ZS; i += NTc) z32[i] = 0;  // both buffers (h(0)=0)
    }
    for (int i = tid; i < Lc * NBc; i += NTc) {    // coalesced global, [t][b] LDS
        const int b = i >> 11, t = i & (Lc - 1);
        catb4[t * 4 + b] = (unsigned char)cat_in[(b0 + b) * Lc + t];
        xs04[t * 4 + b]  = (_Float16)(cont_in[(b0 + b) * Lc + t] * w00);
        xs14[t * 4 + b]  = (_Float16)(X_in[(b0 + b) * Lc + t]);
    }
    if (tid < NBc * DECc) {
        const int b = tid >> 6, t = tid & 63;
        catob4[t * 4 + b] = (unsigned char)cat_out[(b0 + b) * DECc + t];
        xo4[t * 4 + b]    = (_Float16)(cont_out[(b0 + b) * DECc + t] * w00);
    }
    for (int i = tid; i < 6 * Hc; i += NTc) {
        const int o = i >> 7, k = i & 127;
        wh_lds[i] = (o == 0) ? Wm[k] : (o == 1) ? Ws[k] : Wv[(o - 2) * Hc + k];
    }
    if (tid == 0) { hb_lds[0] = bm[0]; hb_lds[1] = bs[0]; }
    if (tid < 4)  { hb_lds[2 + tid] = bv[tid]; mu_lds[tid] = 0.0f; }

    // ---- B-fragments (h only): acc tile index == gate type; row = gt*128 + cell ----
    half8 Bf[4][KT];
    float bias_s[4];
    float w16_s[4], w17_s[4];   // Wih cols 16 (cont) and 17 (X / mu)
    #define LOAD_T(WIH, WHH, BB)                                               \
    {                                                                          \
        _Pragma("unroll")                                                      \
        for (int gt = 0; gt < 4; ++gt) {                                       \
            const int row = gt * Hc + cell;                                    \
            _Pragma("unroll")                                                  \
            for (int kt = 0; kt < KT; ++kt) {                                  \
                half8 f;                                                       \
                _Pragma("unroll")                                              \
                for (int j = 0; j < 8; ++j)                                    \
                    f[j] = (_Float16)WHH[row * Hc + 32 * kt + 8 * q + j];      \
                Bf[gt][kt] = f;                                                \
            }                                                                  \
            bias_s[gt] = BB[row];                                              \
            w16_s[gt]  = WIH[row * INc + 16];                                  \
            w17_s[gt]  = WIH[row * INc + 17];                                  \
        }                                                                      \
    }

    LOAD_T(Wih_e, Whh_e, b_e);
    float4v bias4[4];
    #pragma unroll
    for (int gt = 0; gt < 4; ++gt)
        bias4[gt] = (float4v){bias_s[gt], bias_s[gt], bias_s[gt], bias_s[gt]};
    __syncthreads();

    // prologue: xg(0) + cont/X(0) for this lane's batch q
    half4v xg;
    {
        const int c0 = (int)catb4[0 * 4 + q];
        xg = *(const half4v*)(xtab + c0 * 512 + cell * 4);
    }

    int p = 0;
    float c_reg = 0.f;

    // ===================== encoder: 1 barrier/step =====================
    for (int t = 0; t < Lc; ++t) {
        const _Float16* zr = &z_lds[p][0];
        _Float16*       zw = &z_lds[p ^ 1][0];

        // prefetch: cont/X(t) (tail use), table row for t+1 (full-step slack)
        const float cv = (float)xs04[t * 4 + q];
        const float xv = (float)xs14[t * 4 + q];
        const int   tn = (t + 1 < Lc) ? t + 1 : Lc - 1;
        const int   cn = (int)catb4[tn * 4 + q];
        const half4v xg_n = *(const half4v*)(xtab + cn * 512 + cell * 4);

        // h A-frags (4 k-tiles)
        const _Float16* ap = zr + bx * ZS + 8 * q;
        half8 Az[KT];
        #pragma unroll
        for (int kt = 0; kt < KT; ++kt) Az[kt] = *(const half8*)(ap + 32 * kt);

        float4v acc[4];
        #pragma unroll
        for (int gt = 0; gt < 4; ++gt) {
            float4v a = bias4[gt];
            #pragma unroll
            for (int kt = 0; kt < KT; ++kt)
                a = __builtin_amdgcn_mfma_f32_16x16x32_f16(Az[kt], Bf[gt][kt], a, 0, 0, 0);
            acc[gt] = a;
        }

        // gates: in-lane (batch q, cell) + x contribution (table + rank-2)
        const float gi = sel4(acc[0], q) + (float)xg[0] + cv * w16_s[0] + xv * w17_s[0];
        const float gf = sel4(acc[1], q) + (float)xg[1] + cv * w16_s[1] + xv * w17_s[1];
        const float gg = sel4(acc[2], q) + (float)xg[2] + cv * w16_s[2] + xv * w17_s[2];
        const float go = sel4(acc[3], q) + (float)xg[3] + cv * w16_s[3] + xv * w17_s[3];

        const float cn2 = sigm(gf) * c_reg + sigm(gi) * tanh_(gg);
        c_reg = cn2;
        zw[q * ZS + cell] = (_Float16)(sigm(go) * tanh_(cn2));

        xg = xg_n;
        __syncthreads();
        p ^= 1;
    }

    // ===================== decoder =====================
    LOAD_T(Wih_d, Whh_d, b_d);
    #pragma unroll
    for (int gt = 0; gt < 4; ++gt)
        bias4[gt] = (float4v){bias_s[gt], bias_s[gt], bias_s[gt], bias_s[gt]};
    const float bm0 = hb_lds[0], bs0 = hb_lds[1];
    const _Float16* xtabd = xtab + TBL;

    // decoder x(0) = [emb(cat_in[Lc-1]), cont_in[Lc-1]*w00, X_in[Lc-1]] with DEC weights
    {
        const int c0 = (int)catb4[(Lc - 1) * 4 + q];
        xg = *(const half4v*)(xtabd + c0 * 512 + cell * 4);
    }
    const float cv0 = (float)xs04[(Lc - 1) * 4 + q];
    const float sv0 = (float)xs14[(Lc - 1) * 4 + q];

    for (int t = 0; t < DECc; ++t) {
        const _Float16* zr = &z_lds[p][0];
        _Float16*       zw = &z_lds[p ^ 1][0];

        // inputs for this step's x: cont-part and slot-17 part (X for t=0, mu after)
        const float cv = (t == 0) ? cv0 : (float)xo4[(t - 1) * 4 + q];
        const float sv = (t == 0) ? sv0 : mu_lds[q];

        // prefetch table row for t+1 (cat_out[t] feeds x(t+1))
        const int cn = (int)catob4[t * 4 + q];
        const half4v xg_n = *(const half4v*)(xtabd + cn * 512 + cell * 4);

        const _Float16* ap = zr + bx * ZS + 8 * q;
        half8 Az[KT];
        #pragma unroll
        for (int kt = 0; kt < KT; ++kt) Az[kt] = *(const half8*)(ap + 32 * kt);

        float4v acc[4];
        #pragma unroll
        for (int gt = 0; gt < 4; ++gt) {
            float4v a = bias4[gt];
            #pragma unroll
            for (int kt = 0; kt < KT; ++kt)
                a = __builtin_amdgcn_mfma_f32_16x16x32_f16(Az[kt], Bf[gt][kt], a, 0, 0, 0);
            acc[gt] = a;
        }

        const float gi = sel4(acc[0], q) + (float)xg[0] + cv * w16_s[0] + sv * w17_s[0];
        const float gf = sel4(acc[1], q) + (float)xg[1] + cv * w16_s[1] + sv * w17_s[1];
        const float gg = sel4(acc[2], q) + (float)xg[2] + cv * w16_s[2] + sv * w17_s[2];
        const float go = sel4(acc[3], q) + (float)xg[3] + cv * w16_s[3] + sv * w17_s[3];

        const float cn2 = sigm(gf) * c_reg + sigm(gi) * tanh_(gg);
        c_reg = cn2;
        const float hv = sigm(go) * tanh_(cn2);
        zw[q * ZS + cell] = (_Float16)hv;
        h32_lds[q * 132 + cell] = hv;

        xg = xg_n;
        __syncthreads();

        // heads: 24 dot-products x 16 lanes each (8 strided FMAs + shfl reduce)
        if (tid < 384) {
            const int grp = tid >> 4;       // 0..23, wave-aligned 16-thread groups
            const int l16 = tid & 15;
            const int b   = grp & 3, o = grp >> 2;  // o = 0..5
            float s = 0.0f;
            #pragma unroll
            for (int j = 0; j < 8; ++j) {
                const int k = l16 + 16 * j;
                s += wh_lds[o * Hc + k] * h32_lds[b * 132 + k];
            }
            s += __shfl_xor(s, 1);
            s += __shfl_xor(s, 2);
            s += __shfl_xor(s, 4);
            s += __shfl_xor(s, 8);
            if (l16 == 0) {
                const int gb = b0 + b;
                if (o == 0) {
                    const float mu = s + bm0;
                    out[gb * DECc + t] = mu;
                    mu_lds[b] = mu;   // slot-17 feedback for next step's rank-1 term
                } else if (o == 1) {
                    out[65536 + gb * DECc + t] = softplus_(s + bs0);
                } else {
                    out[131072 + (gb * DECc + t) * 4 + (o - 2)] = s + hb_lds[2 + (o - 2)];
                }
            }
        }
        __syncthreads();
        p ^= 1;
    }
    #undef LOAD_T
}

extern "C" void kernel_launch(void* const* d_in, const int* in_sizes, int n_in,
                              void* d_out, int out_size, void* d_ws, size_t ws_size,
                              hipStream_t stream) {
    _Float16* xtab = (_Float16*)d_ws;   // 2 * 200*512 f16 = 400 KB
    prep_kernel<<<CARD, 512, 0, stream>>>(
        (const float*)d_in[5], (const float*)d_in[7], (const float*)d_in[10], xtab);
    rnnar_kernel<<<1024 / NBc, NTc, 0, stream>>>(
        (const int*)d_in[0],   (const float*)d_in[1],  (const float*)d_in[2],
        (const int*)d_in[3],   (const float*)d_in[4],  (const float*)d_in[5],
        (const float*)d_in[6],
        (const float*)d_in[7], (const float*)d_in[8],  (const float*)d_in[9],
        (const float*)d_in[10],(const float*)d_in[11], (const float*)d_in[12],
        (const float*)d_in[13],(const float*)d_in[14],
        (const float*)d_in[15],(const float*)d_in[16],
        (const float*)d_in[17],(const float*)d_in[18],
        xtab,
        (float*)d_out);
}

// Round 9
// 1155.802 us; speedup vs baseline: 1.0941x; 1.0941x over previous
//
#include <hip/hip_runtime.h>
#include <math.h>

typedef _Float16 half8 __attribute__((ext_vector_type(8)));
typedef float float4v __attribute__((ext_vector_type(4)));

constexpr int Lc   = 2048;  // L_IN
constexpr int DECc = 64;    // DEC_LEN
constexpr int Hc   = 128;   // H
constexpr int EMBc = 16;    // EMB
constexpr int INc  = 18;    // IN_SIZE
constexpr int NBc  = 4;     // batches per block
constexpr int NTc  = 512;   // 8 waves
constexpr int KT   = 5;     // k-tiles of 32 (z padded to 160)
constexpr int CARD = 200;
constexpr int ZS   = 160;   // z stride per batch (halves); 320B -> 2-way (free) on b128 reads

// FINAL (session best, reproduced twice: 1150.3 / 1151.7 us wall, 1215 us steady).
// Latency-bound recurrence: step = ~776 cy MFMA-issue/SIMD (invariant: 512 gates x
// K=160 x 4-batch M-replication, checked vs NBc/tile/K-split/dtype alternatives)
// + ~600 cy phase-locked serial (barrier-synced read->MFMA-chain->LSTM-activation->
// write cycle). Eight structural variants (R2-R6, R8) each improved their targeted
// counter (bank conflicts 11.5M->2.0M, x-gather, writer straggle, -4 MFMAs via
// emb->gate table) and ALL regressed end-to-end 100-250 us: the targeted terms are
// small and collateral scheduling/spill/latency costs exceed them.
//
// Structure: z = [x(18) | h(128) | pad] double-buffered in LDS; 5 uniform k-tiles;
// gate-type-per-accumulator MFMA layout (acc[gt], C-layout col=cell, row=batch)
// so all four gates of one (cell,batch) land in-lane -- no LDS gate shuffle, just
// sel4 (3 cndmask); 72-thread x-writer stages x(t+1) into the write buffer;
// decoder heads via 16-lane split dot-products + shfl reduce; mu feedback through
// z slot 17.

__device__ __forceinline__ float rcp_(float x) { return __builtin_amdgcn_rcpf(x); }
__device__ __forceinline__ float sigm(float x) { return rcp_(1.0f + __expf(-x)); }
__device__ __forceinline__ float tanh_(float x) { return 2.0f * rcp_(1.0f + __expf(-2.0f * x)) - 1.0f; }
__device__ __forceinline__ float softplus_(float x) { return __logf(1.0f + __expf(x)); }

// dynamic 4-element select (3 cndmask) -- replaces the LDS gate shuffle
__device__ __forceinline__ float sel4(float4v v, int q) {
    const float a = (q & 1) ? v[1] : v[0];
    const float b = (q & 1) ? v[3] : v[2];
    return (q & 2) ? b : a;
}

__global__ __launch_bounds__(NTc, 1) void rnnar_kernel(
    const int*   __restrict__ cat_in,  const float* __restrict__ cont_in,
    const float* __restrict__ X_in,    const int*   __restrict__ cat_out,
    const float* __restrict__ cont_out,const float* __restrict__ emb_table,
    const float* __restrict__ cont_w,
    const float* __restrict__ Wih_e, const float* __restrict__ Whh_e, const float* __restrict__ b_e,
    const float* __restrict__ Wih_d, const float* __restrict__ Whh_d, const float* __restrict__ b_d,
    const float* __restrict__ Wm, const float* __restrict__ bm,
    const float* __restrict__ Ws, const float* __restrict__ bs,
    const float* __restrict__ Wv, const float* __restrict__ bv,
    float* __restrict__ out)
{
    __shared__ _Float16      z_lds[2][NBc * ZS];   // 2.5 KB double-buffered z, [b][k]
    __shared__ _Float16      emb_lds[CARD * EMBc]; // 6.4 KB
    __shared__ _Float16      xs0[NBc * Lc];        // 16 KB cont_in * w00
    __shared__ _Float16      xs1[NBc * Lc];        // 16 KB X_in
    __shared__ _Float16      xo_lds[NBc * DECc];   // 512 B cont_out * w00
    __shared__ unsigned char catb[NBc * Lc];       // 8 KB
    __shared__ unsigned char catob[NBc * DECc];    // 256 B
    __shared__ float         h32_lds[NBc * 132];   // 2.1 KB
    __shared__ float         wh_lds[6 * Hc];       // 3 KB
    __shared__ float         hb_lds[8];

    const int tid  = threadIdx.x;
    const int lane = tid & 63;
    const int wv   = tid >> 6;        // wave 0..7
    const int q    = lane >> 4;       // quad 0..3 = this lane's batch
    const int col  = lane & 15;       // cell-local 0..15
    const int cell = 16 * wv + col;   // this lane's cell
    const int bx   = col & 3;         // A-frag batch
    const int b0   = blockIdx.x * NBc;
    const float w00 = cont_w[0];

    const int xk = tid >> 2, xb = tid & 3;   // x-writer role (tid < 72)

    // ---------------- staging ----------------
    {
        int* z32 = (int*)&z_lds[0][0];
        for (int i = tid; i < NBc * ZS; i += NTc) z32[i] = 0;  // both buffers
    }
    for (int i = tid; i < NBc * Lc; i += NTc) {
        const int b = i >> 11, t = i & (Lc - 1);
        catb[i] = (unsigned char)cat_in[(b0 + b) * Lc + t];
        xs0[i]  = (_Float16)(cont_in[(b0 + b) * Lc + t] * w00);
        xs1[i]  = (_Float16)(X_in[(b0 + b) * Lc + t]);
    }
    if (tid < NBc * DECc) {
        const int b = tid >> 6, t = tid & 63;
        catob[tid]  = (unsigned char)cat_out[(b0 + b) * DECc + t];
        xo_lds[tid] = (_Float16)(cont_out[(b0 + b) * DECc + t] * w00);
    }
    for (int i = tid; i < CARD * EMBc; i += NTc) emb_lds[i] = (_Float16)emb_table[i];
    for (int i = tid; i < 6 * Hc; i += NTc) {
        const int o = i >> 7, k = i & 127;
        wh_lds[i] = (o == 0) ? Wm[k] : (o == 1) ? Ws[k] : Wv[(o - 2) * Hc + k];
    }
    if (tid == 0) { hb_lds[0] = bm[0]; hb_lds[1] = bs[0]; }
    if (tid < 4)  { hb_lds[2 + tid] = bv[tid]; }

    // ---- B-fragments: acc tile index == gate type; row = gt*128 + cell ----
    half8 Bf[4][KT];
    float bias_s[4];
    #define LOAD_T(WIH, WHH, BB)                                               \
    {                                                                          \
        _Pragma("unroll")                                                      \
        for (int gt = 0; gt < 4; ++gt) {                                       \
            const int row = gt * Hc + cell;                                    \
            _Pragma("unroll")                                                  \
            for (int kt = 0; kt < KT; ++kt) {                                  \
                half8 f;                                                       \
                _Pragma("unroll")                                              \
                for (int j = 0; j < 8; ++j) {                                  \
                    const int k = 32 * kt + 8 * q + j;                         \
                    float v = 0.0f;                                            \
                    if (k < INc)            v = WIH[row * INc + k];            \
                    else if (k < INc + Hc)  v = WHH[row * Hc + (k - INc)];     \
                    f[j] = (_Float16)v;                                        \
                }                                                              \
                Bf[gt][kt] = f;                                                \
            }                                                                  \
            bias_s[gt] = BB[row];                                              \
        }                                                                      \
    }

    LOAD_T(Wih_e, Whh_e, b_e);
    __syncthreads();

    // x(0) into buffer 0
    if (tid < INc * NBc) {
        _Float16 v;
        if (xk < EMBc)       v = emb_lds[(int)catb[xb * Lc] * EMBc + xk];
        else if (xk == EMBc) v = xs0[xb * Lc];
        else                 v = xs1[xb * Lc];
        z_lds[0][xb * ZS + xk] = v;
    }
    __syncthreads();

    int p = 0;
    float c_reg = 0.f;

    // ===================== encoder: 1 barrier/step, no gate shuffle =====================
    for (int t = 0; t < Lc; ++t) {
        const _Float16* zr = &z_lds[p][0];
        _Float16*       zw = &z_lds[p ^ 1][0];

        // A-frags from z (batch = col&3)
        const _Float16* ap = zr + bx * ZS + 8 * q;
        half8 Az[KT];
        #pragma unroll
        for (int kt = 0; kt < KT; ++kt) Az[kt] = *(const half8*)(ap + 32 * kt);

        float4v acc[4];
        #pragma unroll
        for (int gt = 0; gt < 4; ++gt) {
            float4v a = {bias_s[gt], bias_s[gt], bias_s[gt], bias_s[gt]};
            #pragma unroll
            for (int kt = 0; kt < KT; ++kt)
                a = __builtin_amdgcn_mfma_f32_16x16x32_f16(Az[kt], Bf[gt][kt], a, 0, 0, 0);
            acc[gt] = a;
        }

        // gates land in-lane: batch q, cell = 16wv+col
        const float gi = sel4(acc[0], q);
        const float gf = sel4(acc[1], q);
        const float gg = sel4(acc[2], q);
        const float go = sel4(acc[3], q);

        const float cn = sigm(gf) * c_reg + sigm(gi) * tanh_(gg);
        c_reg = cn;
        zw[q * ZS + INc + cell] = (_Float16)(sigm(go) * tanh_(cn));

        // x(t+1) (clamped: t=Lc-1 writes decoder-init x)
        if (tid < INc * NBc) {
            const int t1 = (t + 1 < Lc) ? t + 1 : Lc - 1;
            _Float16 v;
            if (xk < EMBc)       v = emb_lds[(int)catb[xb * Lc + t1] * EMBc + xk];
            else if (xk == EMBc) v = xs0[xb * Lc + t1];
            else                 v = xs1[xb * Lc + t1];
            zw[xb * ZS + xk] = v;
        }
        __syncthreads();
        p ^= 1;
    }

    // ===================== decoder =====================
    LOAD_T(Wih_d, Whh_d, b_d);
    const float bm0 = hb_lds[0], bs0 = hb_lds[1];

    for (int t = 0; t < DECc; ++t) {
        const _Float16* zr = &z_lds[p][0];
        _Float16*       zw = &z_lds[p ^ 1][0];

        const _Float16* ap = zr + bx * ZS + 8 * q;
        half8 Az[KT];
        #pragma unroll
        for (int kt = 0; kt < KT; ++kt) Az[kt] = *(const half8*)(ap + 32 * kt);

        float4v acc[4];
        #pragma unroll
        for (int gt = 0; gt < 4; ++gt) {
            float4v a = {bias_s[gt], bias_s[gt], bias_s[gt], bias_s[gt]};
            #pragma unroll
            for (int kt = 0; kt < KT; ++kt)
                a = __builtin_amdgcn_mfma_f32_16x16x32_f16(Az[kt], Bf[gt][kt], a, 0, 0, 0);
            acc[gt] = a;
        }

        const float gi = sel4(acc[0], q);
        const float gf = sel4(acc[1], q);
        const float gg = sel4(acc[2], q);
        const float go = sel4(acc[3], q);

        const float cn = sigm(gf) * c_reg + sigm(gi) * tanh_(gg);
        c_reg = cn;
        const float hv = sigm(go) * tanh_(cn);
        zw[q * ZS + INc + cell] = (_Float16)hv;
        h32_lds[q * 132 + cell] = hv;

        // feats_out(t) -> x(t+1); slot 17 (mu) written by heads
        if (tid < INc * NBc && xk < INc - 1) {
            _Float16 v;
            if (xk < EMBc) v = emb_lds[(int)catob[xb * DECc + t] * EMBc + xk];
            else           v = xo_lds[xb * DECc + t];
            zw[xb * ZS + xk] = v;
        }
        __syncthreads();

        // heads: 24 dot-products x 16 lanes each (8 strided FMAs + shfl reduce)
        if (tid < 384) {
            const int grp = tid >> 4;       // 0..23, 16-thread groups (wave-aligned)
            const int l16 = tid & 15;
            const int b   = grp & 3, o = grp >> 2;  // o = 0..5
            float s = 0.0f;
            #pragma unroll
            for (int j = 0; j < 8; ++j) {
                const int k = l16 + 16 * j;
                s += wh_lds[o * Hc + k] * h32_lds[b * 132 + k];
            }
            s += __shfl_xor(s, 1);
            s += __shfl_xor(s, 2);
            s += __shfl_xor(s, 4);
            s += __shfl_xor(s, 8);
            if (l16 == 0) {
                const int gb = b0 + b;
                if (o == 0) {
                    const float mu = s + bm0;
                    out[gb * DECc + t] = mu;
                    zw[b * ZS + (INc - 1)] = (_Float16)mu;   // mu feedback
                } else if (o == 1) {
                    out[65536 + gb * DECc + t] = softplus_(s + bs0);
                } else {
                    out[131072 + (gb * DECc + t) * 4 + (o - 2)] = s + hb_lds[2 + (o - 2)];
                }
            }
        }
        __syncthreads();
        p ^= 1;
    }
    #undef LOAD_T
}

extern "C" void kernel_launch(void* const* d_in, const int* in_sizes, int n_in,
                              void* d_out, int out_size, void* d_ws, size_t ws_size,
                              hipStream_t stream) {
    rnnar_kernel<<<1024 / NBc, NTc, 0, stream>>>(
        (const int*)d_in[0],   (const float*)d_in[1],  (const float*)d_in[2],
        (const int*)d_in[3],   (const float*)d_in[4],  (const float*)d_in[5],
        (const float*)d_in[6],
        (const float*)d_in[7], (const float*)d_in[8],  (const float*)d_in[9],
        (const float*)d_in[10],(const float*)d_in[11], (const float*)d_in[12],
        (const float*)d_in[13],(const float*)d_in[14],
        (const float*)d_in[15],(const float*)d_in[16],
        (const float*)d_in[17],(const float*)d_in[18],
        (float*)d_out);
}